// Round 5
// baseline (359.512 us; speedup 1.0000x reference)
//
#include <hip/hip_runtime.h>

namespace {

typedef __attribute__((ext_vector_type(8)))  short          short8;
typedef __attribute__((ext_vector_type(8)))  unsigned short u16x8;
typedef __attribute__((ext_vector_type(4)))  unsigned short u16x4;
typedef __attribute__((ext_vector_type(4)))  float          f32x4;

constexpr int V  = 200;
constexpr int F  = 64;
constexpr int NT = 512;   // N*T

// ---- ws layout (bytes) ----
constexpr size_t WS_XT  = 0;            // ushort [512][64][224] = 14,680,064 (x^T bf16, 0-padded)
constexpr size_t WS_THT = 14680064;     // ushort [3][64][64]    =     24,576
constexpr size_t WS_ATT = 14704640;     // ushort [8][224][224]  =    802,816 (Att^T bf16, 0-padded)
constexpr size_t WS_AD  = 15507456;     // float  [8][224]       =      7,168 (Att diag, exact f32)

__device__ __forceinline__ unsigned short f2bf(float x) {
    union { float f; unsigned u; } c; c.f = x;
    unsigned r = c.u + 0x7FFF + ((c.u >> 16) & 1);
    return (unsigned short)(r >> 16);
}
__device__ __forceinline__ float bf2f(unsigned short h) {
    union { unsigned u; float f; } c; c.u = ((unsigned)h) << 16;
    return c.f;
}

// ============ P1: xT[b][f][u] = bf16(x[b][u][f]) (513th block: ThT) ============
__global__ __launch_bounds__(256)
void prep_misc(const float* __restrict__ x,
               const float* __restrict__ Theta,
               unsigned short* __restrict__ xT,
               unsigned short* __restrict__ thT)
{
    __shared__ __align__(16) char smem[30464];
    const int bb = blockIdx.x, tid = threadIdx.x;
    if (bb < NT) {
        unsigned short* xs = (unsigned short*)smem;    // [224][68] bf16
        const float* __restrict__ xp = x + (size_t)bb * (V * F);
        for (int idx = tid; idx < 224 * 16; idx += 256) {
            const int u = idx >> 4, fg = idx & 15;
            u16x4 w; w[0] = 0; w[1] = 0; w[2] = 0; w[3] = 0;
            if (u < V) {
                const float4 v4 = *(const float4*)&xp[u * F + 4 * fg];
                w[0] = f2bf(v4.x); w[1] = f2bf(v4.y); w[2] = f2bf(v4.z); w[3] = f2bf(v4.w);
            }
            *(u16x4*)&xs[u * 68 + 4 * fg] = w;
        }
        __syncthreads();
        unsigned short* xo = xT + (size_t)bb * (64 * 224);
        for (int it = 0; it < 8; ++it) {
            const int wid = tid + 256 * it;            // 0..2047
            const int f = wid >> 5, sl = wid & 31;     // 64 f-rows x 32 slots (28 valid)
            if (sl < 28) {
                u16x8 w;
                #pragma unroll
                for (int j = 0; j < 8; ++j) w[j] = xs[(8 * sl + j) * 68 + f];
                *(u16x8*)&xo[f * 224 + 8 * sl] = w;    // 448B contiguous per f-row
            }
        }
    } else {
        float* T = (float*)smem;                       // [64][65] f32
        for (int k = 0; k < 3; ++k) {
            __syncthreads();
            for (int idx = tid; idx < 4096; idx += 256)
                T[(idx >> 6) * 65 + (idx & 63)] = Theta[k * 4096 + idx];
            __syncthreads();
            for (int idx = tid; idx < 4096; idx += 256) {
                const int fo = idx >> 6, f = idx & 63;
                thT[k * 4096 + fo * 64 + f] = f2bf(T[f * 65 + fo]);
            }
        }
    }
}

// ============ P2: AttT[n][v][u] = bf16(Att[n][u][v]) (0-padded) + adiag ============
__global__ __launch_bounds__(256)
void prep_attT(const float* __restrict__ Att,
               unsigned short* __restrict__ attT,
               float* __restrict__ adiag)
{
    __shared__ float T[32][33];
    const int n  = blockIdx.x;
    const int ut = blockIdx.y / 7, vt = blockIdx.y % 7;
    const int tid = threadIdx.x;

    for (int idx = tid; idx < 1024; idx += 256) {
        const int rr = idx >> 5, cc = idx & 31;
        const int u = 32 * ut + rr, v = 32 * vt + cc;
        T[rr][cc] = (u < V && v < V) ? Att[(size_t)n * (V * V) + u * V + v] : 0.f;
    }
    __syncthreads();
    for (int idx = tid; idx < 1024; idx += 256) {
        const int r2 = idx >> 5, c2 = idx & 31;
        attT[(size_t)n * (224 * 224) + (32 * vt + r2) * 224 + 32 * ut + c2] = f2bf(T[c2][r2]);
    }
    if (ut == vt && tid < 32)
        adiag[n * 224 + 32 * vt + tid] = T[tid][tid];
}

// ============ G: fused kernel, fully prefetched K loop ============
// grid 1024, swizzled so the two v-halves of batch b share an XCD.
// Per kt (32 u's): all three global streams (S slab, S rows, AttT rows)
// register-prefetched one kt ahead -> LDS/VALU build of A1/A2 bf16
// (A1=-m*Att[u][v], A2=2m^2*Att[u][v], m=min(S[v][u],S[u][v])) + d accum
// -> MFMA. Epilogue: LDS-staged x, Chebyshev diag terms + Theta + relu.
__global__ __launch_bounds__(256, 4)
void cheb_fused(const float* __restrict__ x,
                const float* __restrict__ S,
                const unsigned short* __restrict__ attT,
                const float* __restrict__ adiag,
                const unsigned short* __restrict__ thT,
                const unsigned short* __restrict__ xT,
                float* __restrict__ out)
{
    __shared__ __align__(16) char smem[40512];
    // K loop:
    float*          sru = (float*)smem;                      // [32][113] f32 S[u][v-range] = 14,464
    unsigned short* A1  = (unsigned short*)(smem + 14464);   // [112][32] bf16 = 7,168
    unsigned short* A2  = (unsigned short*)(smem + 21632);   // [112][32] bf16 = 7,168 (ends 28,800)
    // epilogue (after K loop done):
    unsigned short* ys  = (unsigned short*)smem;             // [112][68] = 15,232
    unsigned short* ThS = (unsigned short*)(smem + 15232);   // [64][68]  =  8,704 (ends 23,936)
    unsigned short* xe  = (unsigned short*)(smem + 23936);   // [112][68] = 15,232 (ends 39,168)
    // persistent:
    float* dbuf = (float*)(smem + 39168);                    // [112] d accum -> cbuf
    float* sdb  = (float*)(smem + 39616);                    // [112] S[v][v]
    float* adb  = (float*)(smem + 40064);                    // [112] Att[v][v]

    const int tid = threadIdx.x;
    // swizzle: blocks u and u+8 (same XCD, round-robin mod 8) are the two
    // halves of the same b -> shared xT/S/AttT in that XCD's L2.
    const int ub = blockIdx.x;
    const int h  = (ub >> 3) & 1;
    const int b  = (ub & 7) | ((ub >> 4) << 3);
    const int n  = b >> 6;
    const int v0 = h * 112;
    const int NVL = h ? 96 : 112;     // local v-rows
    const int NV4 = NVL >> 2;         // float4 slots per slab row

    const float* __restrict__ Sp  = S + (size_t)b * (V * V);
    const unsigned short* __restrict__ atp = attT + (size_t)n * (224 * 224);
    const float* __restrict__ xp  = x + (size_t)b * (V * F);
    const unsigned short* __restrict__ xTp = xT + (size_t)b * (64 * 224);
    float* __restrict__ op = out + (size_t)b * (V * F);

    if (tid < 112) {
        dbuf[tid] = 0.f; sdb[tid] = 0.f;
        adb[tid] = adiag[n * 224 + v0 + tid];   // exact f32 Att diag
    }

    const int wave = tid >> 6, lane = tid & 63, q = lane >> 4, ln = lane & 15;
    int myBase, myCnt;
    if (h == 0) { myCnt = (wave < 3) ? 2 : 1; myBase = 2 * wave; }        // tiles 0..6
    else        { myCnt = (wave < 2) ? 2 : 1; myBase = (wave < 2) ? 2 * wave : 2 + wave; } // 0..5

    f32x4 acc1[2][4], acc2[2][4];
    #pragma unroll
    for (int i = 0; i < 2; ++i)
        #pragma unroll
        for (int j = 0; j < 4; ++j) { acc1[i][j] = (f32x4)0.f; acc2[i][j] = (f32x4)0.f; }

    // ---- register prefetch of ALL K-loop global streams, one kt ahead ----
    float4 spf[4];    // S slab:  S[u][v-range]        (slab mapping)
    float4 scpf[4];   // S rows:  S[v][u-chunk]        (item mapping)
    u16x4  apf[4];    // AttT:    Att^T[v][u-chunk]    (item mapping)
    auto load_slab = [&](int kt) {
        #pragma unroll
        for (int c = 0; c < 4; ++c) {
            const int idx = tid + 256 * c;
            // slab mapping
            const int ul = idx >> 5, sl = idx & 31;
            const int u = 32 * kt + ul, vv = v0 + 4 * sl;
            float4 z = make_float4(0.f, 0.f, 0.f, 0.f);
            if (sl < NV4 && u < V && vv < V)
                z = *(const float4*)&Sp[u * V + vv];       // contiguous per u-row
            spf[c] = z;
            // item mapping
            const int vl = idx >> 3, ug = idx & 7;
            const int v = v0 + vl, u0 = 32 * kt + 4 * ug;
            float4 r = make_float4(0.f, 0.f, 0.f, 0.f);
            u16x4 a; a[0] = 0; a[1] = 0; a[2] = 0; a[3] = 0;
            if (idx < NVL * 8) {
                if (v < V && u0 < V) r = *(const float4*)&Sp[v * V + u0];
                a = *(const u16x4*)&atp[v * 224 + u0];     // 0-padded rows/cols
            }
            scpf[c] = r; apf[c] = a;
        }
    };
    load_slab(0);
    __syncthreads();

    #pragma unroll 1
    for (int kt = 0; kt < 7; ++kt) {
        // ---- phase S: prefetched slab regs -> LDS ----
        #pragma unroll
        for (int c = 0; c < 4; ++c) {
            const int idx = tid + 256 * c;
            const int ul = idx >> 5, sl = idx & 31;
            if (sl < NV4) *(float4*)&sru[ul * 113 + 4 * sl] = spf[c];
        }
        __syncthreads();   // sru ready; MFMA(kt-1) done -> A-tiles free

        // ---- phase A: pure reg/LDS compute of A1/A2 + d/sd ----
        short8 bcur[4];
        #pragma unroll
        for (int ft = 0; ft < 4; ++ft)
            bcur[ft] = *(const short8*)&xTp[(16 * ft + ln) * 224 + 32 * kt + 8 * q];
        #pragma unroll
        for (int c = 0; c < 4; ++c) {
            const int idx = tid + 256 * c;
            if (idx < NVL * 8) {
                const int vl = idx >> 3, ug = idx & 7;
                const int v = v0 + vl;
                const int u0 = 32 * kt + 4 * ug;
                const float4 sc = scpf[c];
                const u16x4  a4 = apf[c];
                float rs = 0.f;
                u16x4 w1, w2;
                #pragma unroll
                for (int j = 0; j < 4; ++j) {
                    const int u = u0 + j;
                    const float srt = sru[(4 * ug + j) * 113 + vl];   // S[u][v] (0-padded)
                    const float scj = (j == 0) ? sc.x : (j == 1) ? sc.y : (j == 2) ? sc.z : sc.w;
                    const float att = bf2f(a4[j]);                    // Att[u][v] (0-padded)
                    const float m = fminf(scj, srt);
                    rs += m;                                          // d includes diagonal
                    float a1, a2;
                    if (u == v) {
                        a1 = 0.f; a2 = 0.f;
                        sdb[vl] = m;                                  // S[v][v] exact
                    } else {
                        a1 = -m * att;
                        a2 = 2.0f * m * m * att;
                    }
                    w1[j] = f2bf(a1); w2[j] = f2bf(a2);
                }
                *(u16x4*)&A1[vl * 32 + 4 * ug] = w1;
                *(u16x4*)&A2[vl * 32 + 4 * ug] = w2;
                rs += __shfl_xor(rs, 1); rs += __shfl_xor(rs, 2); rs += __shfl_xor(rs, 4);
                if (ug == 0 && v < V) dbuf[vl] += rs;   // unique writer per vl per kt
            }
        }
        if (kt < 6) load_slab(kt + 1);      // in flight across MFMA + barriers
        __syncthreads();   // A-tiles ready

        // ---- phase M: MFMA ----
        #pragma unroll
        for (int vi = 0; vi < 2; ++vi) {
            if (vi < myCnt) {
                const int row = (myBase + vi) * 16 + ln;
                const short8 af1 = *(const short8*)&A1[row * 32 + 8 * q];
                const short8 af2 = *(const short8*)&A2[row * 32 + 8 * q];
                #pragma unroll
                for (int ft = 0; ft < 4; ++ft) {
                    acc1[vi][ft] = __builtin_amdgcn_mfma_f32_16x16x32_bf16(af1, bcur[ft], acc1[vi][ft], 0, 0, 0);
                    acc2[vi][ft] = __builtin_amdgcn_mfma_f32_16x16x32_bf16(af2, bcur[ft], acc2[vi][ft], 0, 0, 0);
                }
            }
        }
    }

    __syncthreads();                       // K loop fully done; A-tiles/slab dead
    if (tid < 112) dbuf[tid] = dbuf[tid] - 1.0f - sdb[tid];   // cbuf = d - 1 - S_vv
    // stage x -> bf16 xe (read once, used by all 3 epilogue passes)
    for (int idx = tid; idx < NVL * 16; idx += 256) {
        const int vl = idx >> 4, fg = idx & 15;
        const int v = v0 + vl;
        u16x4 w; w[0] = 0; w[1] = 0; w[2] = 0; w[3] = 0;
        if (v < V) {
            const float4 xv = *(const float4*)&xp[v * F + 4 * fg];
            w[0] = f2bf(xv.x); w[1] = f2bf(xv.y); w[2] = f2bf(xv.z); w[3] = f2bf(xv.w);
        }
        *(u16x4*)&xe[vl * 68 + 4 * fg] = w;
    }

    // ---- epilogue: out-tiles += mfma(ys_k, ThT_k) for k = 1, 2, 0 ----
    f32x4 ot[2][4];
    #pragma unroll
    for (int i = 0; i < 2; ++i)
        #pragma unroll
        for (int j = 0; j < 4; ++j) ot[i][j] = (f32x4)0.f;

    #pragma unroll
    for (int pass = 0; pass < 3; ++pass) {
        const int k = (pass == 0) ? 1 : (pass == 1) ? 2 : 0;
        __syncthreads();   // xe/cbuf ready (pass 0); prev MFMA reads done

        if (k == 0) {
            for (int idx = tid; idx < NVL * 16; idx += 256) {
                const int vl = idx >> 4, fg = idx & 15;
                const int v = v0 + vl;
                u16x4 w; w[0] = 0; w[1] = 0; w[2] = 0; w[3] = 0;
                if (v < V) {
                    const float av = adb[vl];
                    #pragma unroll
                    for (int e = 0; e < 4; ++e)
                        w[e] = f2bf(av * bf2f(xe[vl * 68 + 4 * fg + e]));
                }
                *(u16x4*)&ys[vl * 68 + 4 * fg] = w;
            }
        } else {
            #pragma unroll
            for (int vi = 0; vi < 2; ++vi) {
                if (vi < myCnt) {
                    const int lt = myBase + vi;
                    #pragma unroll
                    for (int ft = 0; ft < 4; ++ft) {
                        const f32x4 a = (k == 1) ? acc1[vi][ft] : acc2[vi][ft];
                        #pragma unroll
                        for (int reg = 0; reg < 4; ++reg) {
                            const int vl = lt * 16 + 4 * q + reg;
                            const int v = v0 + vl;
                            float val = 0.f;
                            if (v < V) {
                                const float cc = dbuf[vl];
                                const float dc = ((k == 1) ? cc : (2.0f * cc * cc - 1.0f)) * adb[vl];
                                val = a[reg] + dc * bf2f(xe[vl * 68 + 16 * ft + ln]);
                            }
                            ys[vl * 68 + 16 * ft + ln] = f2bf(val);
                        }
                    }
                }
            }
        }
        for (int idx = tid; idx < 512; idx += 256) {
            const int fo = idx >> 3, ch = idx & 7;
            *(u16x8*)&ThS[fo * 68 + 8 * ch] =
                *(const u16x8*)&thT[k * 4096 + fo * 64 + 8 * ch];
        }
        __syncthreads();
        #pragma unroll
        for (int vi = 0; vi < 2; ++vi) {
            if (vi < myCnt) {
                const int vrow = (myBase + vi) * 16 + ln;
                #pragma unroll
                for (int ks = 0; ks < 2; ++ks) {
                    const short8 af = *(const short8*)&ys[vrow * 68 + 32 * ks + 8 * q];
                    #pragma unroll
                    for (int fot = 0; fot < 4; ++fot) {
                        const short8 bf = *(const short8*)&ThS[(16 * fot + ln) * 68 + 32 * ks + 8 * q];
                        ot[vi][fot] = __builtin_amdgcn_mfma_f32_16x16x32_bf16(af, bf, ot[vi][fot], 0, 0, 0);
                    }
                }
            }
        }
    }

    // ---- relu + store ----
    #pragma unroll
    for (int vi = 0; vi < 2; ++vi) {
        if (vi < myCnt) {
            const int lt = myBase + vi;
            #pragma unroll
            for (int fot = 0; fot < 4; ++fot) {
                #pragma unroll
                for (int reg = 0; reg < 4; ++reg) {
                    const int v = v0 + lt * 16 + 4 * q + reg;
                    if (v < V)
                        op[v * F + 16 * fot + ln] = fmaxf(ot[vi][fot][reg], 0.f);
                }
            }
        }
    }
}

} // namespace

extern "C" void kernel_launch(void* const* d_in, const int* in_sizes, int n_in,
                              void* d_out, int out_size, void* d_ws, size_t ws_size,
                              hipStream_t stream) {
    const float* x     = (const float*)d_in[0];
    const float* Att   = (const float*)d_in[1];
    const float* S     = (const float*)d_in[2];
    const float* Theta = (const float*)d_in[3];
    float* out         = (float*)d_out;

    char* ws = (char*)d_ws;
    unsigned short* xT   = (unsigned short*)(ws + WS_XT);
    unsigned short* thT  = (unsigned short*)(ws + WS_THT);
    unsigned short* attT = (unsigned short*)(ws + WS_ATT);
    float* adiag         = (float*)(ws + WS_AD);

    hipLaunchKernelGGL(prep_misc, dim3(NT + 1), dim3(256), 0, stream, x, Theta, xT, thT);
    hipLaunchKernelGGL(prep_attT, dim3(8, 49),  dim3(256), 0, stream, Att, attT, adiag);
    hipLaunchKernelGGL(cheb_fused, dim3(2 * NT), dim3(256), 0, stream,
                       x, S, attT, adiag, thT, xT, out);
}

// Round 6
// 233.532 us; speedup vs baseline: 1.5395x; 1.5395x over previous
//
#include <hip/hip_runtime.h>

namespace {

typedef __attribute__((ext_vector_type(8)))  short          short8;
typedef __attribute__((ext_vector_type(8)))  unsigned short u16x8;
typedef __attribute__((ext_vector_type(4)))  unsigned short u16x4;
typedef __attribute__((ext_vector_type(4)))  float          f32x4;

constexpr int V  = 200;
constexpr int F  = 64;
constexpr int NT = 512;   // N*T
constexpr int VP = 208;   // 13 x 16

// ---- ws layout (bytes) ----
// Ac : ushort [512][13 tile][7 kt][2 mat][64 lane][8]  = 95,420,416
// xTf: ushort [512][7 kt][4 ft][64 lane][8]            = 14,680,064
// thT: ushort [3][64][64]                              =     24,576
// d  : float  [512][208]  (atomic; holds d-1-S_vv)     =    425,984
// adg: float  [8][208]                                 =      6,656
constexpr size_t WS_AC  = 0;
constexpr size_t WS_XTF = 95420416;
constexpr size_t WS_THT = 110100480;
constexpr size_t WS_D   = 110125056;
constexpr size_t WS_ADG = 110551040;   // end 110,557,696

__device__ __forceinline__ unsigned short f2bf(float x) {
    union { float f; unsigned u; } c; c.f = x;
    unsigned r = c.u + 0x7FFF + ((c.u >> 16) & 1);
    return (unsigned short)(r >> 16);
}

// ============ P1: xTf B-fragments + thT (513th block) ============
__global__ __launch_bounds__(256)
void prep_misc(const float* __restrict__ x,
               const float* __restrict__ Theta,
               unsigned short* __restrict__ xTf,
               unsigned short* __restrict__ thT)
{
    __shared__ __align__(16) char smem[30464];
    const int bb = blockIdx.x, tid = threadIdx.x;
    if (bb < NT) {
        unsigned short* xs = (unsigned short*)smem;    // [224][68] bf16
        const float* __restrict__ xp = x + (size_t)bb * (V * F);
        for (int idx = tid; idx < 224 * 16; idx += 256) {
            const int u = idx >> 4, fg = idx & 15;
            u16x4 w; w[0] = 0; w[1] = 0; w[2] = 0; w[3] = 0;
            if (u < V) {
                const float4 v4 = *(const float4*)&xp[u * F + 4 * fg];
                w[0] = f2bf(v4.x); w[1] = f2bf(v4.y); w[2] = f2bf(v4.z); w[3] = f2bf(v4.w);
            }
            *(u16x4*)&xs[u * 68 + 4 * fg] = w;
        }
        __syncthreads();
        // fragment order: frag = kt*4+ft; lane holds x[u=32kt+8q+j][f=16ft+ln]
        unsigned short* xo = xTf + (size_t)bb * 14336;
        for (int it = 0; it < 7; ++it) {
            const int wid = tid + 256 * it;            // 0..1791
            const int frag = wid >> 6, lane = wid & 63;
            const int kt = frag >> 2, ft = frag & 3;
            const int q = lane >> 4, ln = lane & 15;
            u16x8 w;
            #pragma unroll
            for (int j = 0; j < 8; ++j)
                w[j] = xs[(32 * kt + 8 * q + j) * 68 + 16 * ft + ln];
            *(u16x8*)&xo[frag * 512 + lane * 8] = w;
        }
    } else {
        float* T = (float*)smem;                       // [64][65] f32
        for (int k = 0; k < 3; ++k) {
            __syncthreads();
            for (int idx = tid; idx < 4096; idx += 256)
                T[(idx >> 6) * 65 + (idx & 63)] = Theta[k * 4096 + idx];
            __syncthreads();
            for (int idx = tid; idx < 4096; idx += 256) {
                const int fo = idx >> 6, f = idx & 63;
                thT[k * 4096 + fo * 64 + f] = f2bf(T[f * 65 + fo]);
            }
        }
    }
}

// ============ P2: tile-pair S_min -> A1/A2 fragment file + d + adiag ============
// grid (512, 28): pair (ti<=tj). S read once. d_ws accumulates
// sum_u min(S[v][u],S[u][v]) via shuffle+atomics; diag block folds in -1-S_vv.
// A1[v][u] = -m*Att[u][v], A2[v][u] = 2m^2*Att[u][v] (0 on u==v), written
// bf16 in MFMA A-fragment order (lane=16q+ln holds A[v=t*16+ln][u=kt*32+8q+j]).
__global__ __launch_bounds__(256)
void prep_A(const float* __restrict__ S,
            const float* __restrict__ Att,
            unsigned short* __restrict__ Ac,
            float* __restrict__ d_ws,
            float* __restrict__ adiag)
{
    __shared__ float As[32][33];   // S  [ti-rows][tj-cols]
    __shared__ float Bs[32][33];   // S  [tj-rows][ti-cols]
    __shared__ float Ts[32][33];   // Att[ti-rows][tj-cols]
    __shared__ float Us[32][33];   // Att[tj-rows][ti-cols]
    __shared__ float Ms[32][33];   // min tile (ti-rows, tj-cols)

    const int b = blockIdx.x, n = b >> 6, tid = threadIdx.x;
    int rem = blockIdx.y, ti = 0;
    while (rem >= 7 - ti) { rem -= 7 - ti; ++ti; }
    const int tj = ti + rem;
    const bool diag = (ti == tj);

    const float* __restrict__ Sp = S   + (size_t)b * (V * V);
    const float* __restrict__ Ap = Att + (size_t)n * (V * V);

    const int r = tid >> 3, cg = tid & 7, c0 = 4 * cg;

    {
        const int gr = 32 * ti + r, gc = 32 * tj + c0;
        float4 a = make_float4(0.f, 0.f, 0.f, 0.f);
        float4 t = make_float4(0.f, 0.f, 0.f, 0.f);
        if (gr < V && gc < V) {
            a = *(const float4*)&Sp[gr * V + gc];
            t = *(const float4*)&Ap[gr * V + gc];
        }
        As[r][c0+0] = a.x; As[r][c0+1] = a.y; As[r][c0+2] = a.z; As[r][c0+3] = a.w;
        Ts[r][c0+0] = t.x; Ts[r][c0+1] = t.y; Ts[r][c0+2] = t.z; Ts[r][c0+3] = t.w;
        if (!diag) {
            const int hr = 32 * tj + r, hc = 32 * ti + c0;
            float4 bb = make_float4(0.f, 0.f, 0.f, 0.f);
            float4 uu = make_float4(0.f, 0.f, 0.f, 0.f);
            if (hr < V && hc < V) {
                bb = *(const float4*)&Sp[hr * V + hc];
                uu = *(const float4*)&Ap[hr * V + hc];
            }
            Bs[r][c0+0] = bb.x; Bs[r][c0+1] = bb.y; Bs[r][c0+2] = bb.z; Bs[r][c0+3] = bb.w;
            Us[r][c0+0] = uu.x; Us[r][c0+1] = uu.y; Us[r][c0+2] = uu.z; Us[r][c0+3] = uu.w;
        }
    }
    __syncthreads();

    // Ms + row-sums -> d[32ti+r]; diag folds -1-S_vv; adiag
    {
        float rs = 0.f;
        #pragma unroll
        for (int e = 0; e < 4; ++e) {
            const int c = c0 + e;
            const float tw = diag ? As[c][r] : Bs[c][r];
            const float m = fminf(As[r][c], tw);
            Ms[r][c] = m;
            rs += m;
        }
        rs += __shfl_xor(rs, 1); rs += __shfl_xor(rs, 2); rs += __shfl_xor(rs, 4);
        const int vg = 32 * ti + r;
        if (cg == 0 && vg < V) {
            const float extra = diag ? (-1.0f - As[r][r]) : 0.0f;
            atomicAdd(&d_ws[b * VP + vg], rs + extra);
            if (diag) adiag[n * VP + vg] = Ts[r][r];
        }
    }
    __syncthreads();   // Ms complete

    if (!diag) {       // col-sums -> d[32tj+r]
        float ts = 0.f;
        #pragma unroll
        for (int e = 0; e < 4; ++e) ts += Ms[c0 + e][r];
        ts += __shfl_xor(ts, 1); ts += __shfl_xor(ts, 2); ts += __shfl_xor(ts, 4);
        if (cg == 0 && 32 * tj + r < V)
            atomicAdd(&d_ws[b * VP + 32 * tj + r], ts);
    }

    // ---- fragment writes ----
    const int jh = tid & 1, lane = (tid >> 1) & 63, sub = tid >> 7;
    const int rr = lane & 15, qq = lane >> 4;
    const int vl = sub * 16 + rr;          // 0..31 within the 32-row block
    const int ub = 8 * qq + 4 * jh;        // u_local base

    // orientation 1: v in ti-block (tiles 2ti+sub), kt = tj
    if (2 * ti + sub < 13) {
        u16x4 w1, w2;
        #pragma unroll
        for (int e = 0; e < 4; ++e) {
            const int ul = ub + e;
            const float m   = Ms[vl][ul];
            const float att = diag ? Ts[ul][vl] : Us[ul][vl];   // Att[u][v]
            const bool dz = diag && (ul == vl);
            w1[e] = f2bf(dz ? 0.f : -m * att);
            w2[e] = f2bf(dz ? 0.f : 2.0f * m * m * att);
        }
        const size_t base = ((size_t)(b * 13 + 2 * ti + sub) * 7 + tj) * 1024;
        *(u16x4*)&Ac[base +       lane * 8 + jh * 4] = w1;
        *(u16x4*)&Ac[base + 512 + lane * 8 + jh * 4] = w2;
    }
    // mirror: v in tj-block (tiles 2tj+sub), kt = ti
    if (!diag && 2 * tj + sub < 13) {
        u16x4 w1, w2;
        #pragma unroll
        for (int e = 0; e < 4; ++e) {
            const int ul = ub + e;
            const float m   = Ms[ul][vl];          // min(S[v'][u'],S[u'][v'])
            const float att = Ts[ul][vl];          // Att[u'=32ti+ul][v'=32tj+vl]
            w1[e] = f2bf(-m * att);
            w2[e] = f2bf(2.0f * m * m * att);
        }
        const size_t base = ((size_t)(b * 13 + 2 * tj + sub) * 7 + ti) * 1024;
        *(u16x4*)&Ac[base +       lane * 8 + jh * 4] = w1;
        *(u16x4*)&Ac[base + 512 + lane * 8 + jh * 4] = w2;
    }
}

// ============ G: streaming MFMA kernel — no LDS/barriers in K loop ============
// grid 1024 (XCD-swizzled pairs). Per block: 7 (h=0) / 6 (h=1) v-tiles.
// xTf staged to LDS once; A1/A2 fragments stream from global, double-buffered
// in regs (1KB coalesced wave loads). Epilogue: 3-pass Theta MFMA (R0 lineage).
__global__ __launch_bounds__(256, 4)
void cheb_stream(const float* __restrict__ x,
                 const unsigned short* __restrict__ Ac,
                 const float* __restrict__ d_ws,
                 const float* __restrict__ adiag,
                 const unsigned short* __restrict__ thT,
                 const unsigned short* __restrict__ xTf,
                 float* __restrict__ out)
{
    __shared__ __align__(16) char smem[29696];
    unsigned short* xTs = (unsigned short*)smem;            // 28,672 B (K loop)
    unsigned short* ys  = (unsigned short*)smem;            // [112][72]*2 = 16,128 (epi)
    unsigned short* ThS = (unsigned short*)(smem + 16128);  // [64][72]*2 = 9,216 (epi)
    float* dbuf = (float*)(smem + 28672);                   // [112] = c = d-1-S_vv
    float* adb  = (float*)(smem + 29120);                   // [112] Att[v][v]

    const int tid = threadIdx.x;
    const int ub_ = blockIdx.x;
    const int h   = (ub_ >> 3) & 1;
    const int b   = (ub_ & 7) | ((ub_ >> 4) << 3);
    const int n   = b >> 6;
    const int v0  = h * 112;

    // stage xTf -> LDS (coalesced, once)
    const unsigned short* __restrict__ xfp = xTf + (size_t)b * 14336;
    #pragma unroll
    for (int it = 0; it < 7; ++it) {
        const int o = it * 2048 + tid * 8;
        *(u16x8*)&xTs[o] = *(const u16x8*)&xfp[o];
    }
    if (tid < 112) {
        const int gv = v0 + tid;
        dbuf[tid] = (gv < VP) ? d_ws[b * VP + gv] : 0.f;
        adb[tid]  = (gv < VP) ? adiag[n * VP + gv] : 0.f;
    }

    const int wave = tid >> 6, lane = tid & 63, q = lane >> 4, ln = lane & 15;
    int myBase, myCnt;
    if (h == 0) { myCnt = (wave < 3) ? 2 : 1; myBase = 2 * wave; }
    else        { myCnt = (wave < 2) ? 2 : 1; myBase = (wave < 2) ? 2 * wave : 2 + wave; }

    const float* __restrict__ xp = x + (size_t)b * (V * F);
    float* __restrict__ op = out + (size_t)b * (V * F);

    f32x4 acc1[2][4], acc2[2][4];
    #pragma unroll
    for (int i = 0; i < 2; ++i)
        #pragma unroll
        for (int j = 0; j < 4; ++j) { acc1[i][j] = (f32x4)0.f; acc2[i][j] = (f32x4)0.f; }

    // A-fragment bases (ushort index at kt=0)
    size_t fb0 = ((size_t)(b * 13 + 7 * h + myBase) * 7) * 1024 + lane * 8;
    size_t fb1 = ((size_t)(b * 13 + 7 * h + myBase + 1) * 7) * 1024 + lane * 8;

    short8 a1c[2], a2c[2], a1n[2], a2n[2];
    a1c[0] = *(const short8*)&Ac[fb0];
    a2c[0] = *(const short8*)&Ac[fb0 + 512];
    if (myCnt > 1) {
        a1c[1] = *(const short8*)&Ac[fb1];
        a2c[1] = *(const short8*)&Ac[fb1 + 512];
    }
    __syncthreads();   // xTs ready

    #pragma unroll 1
    for (int kt = 0; kt < 7; ++kt) {
        if (kt < 6) {
            const size_t o = (size_t)(kt + 1) * 1024;
            a1n[0] = *(const short8*)&Ac[fb0 + o];
            a2n[0] = *(const short8*)&Ac[fb0 + o + 512];
            if (myCnt > 1) {
                a1n[1] = *(const short8*)&Ac[fb1 + o];
                a2n[1] = *(const short8*)&Ac[fb1 + o + 512];
            }
        }
        short8 bfr[4];
        #pragma unroll
        for (int ft = 0; ft < 4; ++ft)
            bfr[ft] = *(const short8*)&xTs[(kt * 4 + ft) * 512 + lane * 8];
        #pragma unroll
        for (int vi = 0; vi < 2; ++vi) {
            if (vi < myCnt) {
                #pragma unroll
                for (int ft = 0; ft < 4; ++ft) {
                    acc1[vi][ft] = __builtin_amdgcn_mfma_f32_16x16x32_bf16(a1c[vi], bfr[ft], acc1[vi][ft], 0, 0, 0);
                    acc2[vi][ft] = __builtin_amdgcn_mfma_f32_16x16x32_bf16(a2c[vi], bfr[ft], acc2[vi][ft], 0, 0, 0);
                }
            }
        }
        #pragma unroll
        for (int vi = 0; vi < 2; ++vi) { a1c[vi] = a1n[vi]; a2c[vi] = a2n[vi]; }
    }

    // ---- epilogue: out-tiles += mfma(ys_k, ThT_k) for k = 1, 2, 0 ----
    f32x4 ot[2][4];
    #pragma unroll
    for (int i = 0; i < 2; ++i)
        #pragma unroll
        for (int j = 0; j < 4; ++j) ot[i][j] = (f32x4)0.f;

    #pragma unroll
    for (int pass = 0; pass < 3; ++pass) {
        const int k = (pass == 0) ? 1 : (pass == 1) ? 2 : 0;
        __syncthreads();   // K-loop xTs reads done / prev pass MFMA reads done

        if (k == 0) {
            for (int idx = tid; idx < 112 * 16; idx += 256) {
                const int vl = idx >> 4, fg = idx & 15;
                const int v = v0 + vl;
                u16x4 w; w[0] = 0; w[1] = 0; w[2] = 0; w[3] = 0;
                if (v < V && vl < 112) {
                    const float av = adb[vl];
                    const float4 xv = *(const float4*)&xp[v * F + 4 * fg];
                    w[0] = f2bf(av * xv.x); w[1] = f2bf(av * xv.y);
                    w[2] = f2bf(av * xv.z); w[3] = f2bf(av * xv.w);
                }
                *(u16x4*)&ys[vl * 72 + 4 * fg] = w;
            }
        } else {
            #pragma unroll
            for (int vi = 0; vi < 2; ++vi) {
                if (vi < myCnt) {
                    const int lt = myBase + vi;
                    #pragma unroll
                    for (int ft = 0; ft < 4; ++ft) {
                        const f32x4 a = (k == 1) ? acc1[vi][ft] : acc2[vi][ft];
                        #pragma unroll
                        for (int reg = 0; reg < 4; ++reg) {
                            const int vl = lt * 16 + 4 * q + reg;
                            const int v = v0 + vl;
                            float val = 0.f;
                            if (v < V) {
                                const float cc = dbuf[vl];
                                const float dc = ((k == 1) ? cc : (2.0f * cc * cc - 1.0f)) * adb[vl];
                                val = a[reg] + dc * xp[v * F + 16 * ft + ln];
                            }
                            ys[vl * 72 + 16 * ft + ln] = f2bf(val);
                        }
                    }
                }
            }
        }
        for (int idx = tid; idx < 512; idx += 256) {
            const int fo = idx >> 3, ch = idx & 7;
            *(u16x8*)&ThS[fo * 72 + 8 * ch] =
                *(const u16x8*)&thT[k * 4096 + fo * 64 + 8 * ch];
        }
        __syncthreads();
        #pragma unroll
        for (int vi = 0; vi < 2; ++vi) {
            if (vi < myCnt) {
                const int vrow = (myBase + vi) * 16 + ln;
                #pragma unroll
                for (int ks = 0; ks < 2; ++ks) {
                    const short8 af = *(const short8*)&ys[vrow * 72 + 32 * ks + 8 * q];
                    #pragma unroll
                    for (int fot = 0; fot < 4; ++fot) {
                        const short8 bf = *(const short8*)&ThS[(16 * fot + ln) * 72 + 32 * ks + 8 * q];
                        ot[vi][fot] = __builtin_amdgcn_mfma_f32_16x16x32_bf16(af, bf, ot[vi][fot], 0, 0, 0);
                    }
                }
            }
        }
    }

    // ---- relu + store ----
    #pragma unroll
    for (int vi = 0; vi < 2; ++vi) {
        if (vi < myCnt) {
            const int lt = myBase + vi;
            #pragma unroll
            for (int fot = 0; fot < 4; ++fot) {
                #pragma unroll
                for (int reg = 0; reg < 4; ++reg) {
                    const int v = v0 + lt * 16 + 4 * q + reg;
                    if (v < V)
                        op[v * F + 16 * fot + ln] = fmaxf(ot[vi][fot][reg], 0.f);
                }
            }
        }
    }
}

} // namespace

extern "C" void kernel_launch(void* const* d_in, const int* in_sizes, int n_in,
                              void* d_out, int out_size, void* d_ws, size_t ws_size,
                              hipStream_t stream) {
    const float* x     = (const float*)d_in[0];
    const float* Att   = (const float*)d_in[1];
    const float* S     = (const float*)d_in[2];
    const float* Theta = (const float*)d_in[3];
    float* out         = (float*)d_out;

    char* ws = (char*)d_ws;
    unsigned short* Ac  = (unsigned short*)(ws + WS_AC);
    unsigned short* xTf = (unsigned short*)(ws + WS_XTF);
    unsigned short* thT = (unsigned short*)(ws + WS_THT);
    float* d_sum        = (float*)(ws + WS_D);
    float* adiag        = (float*)(ws + WS_ADG);

    // d accumulates via atomicAdd -> must start at 0 every call
    hipMemsetAsync(d_sum, 0, (size_t)NT * VP * sizeof(float), stream);

    hipLaunchKernelGGL(prep_misc,   dim3(NT + 1), dim3(256), 0, stream, x, Theta, xTf, thT);
    hipLaunchKernelGGL(prep_A,      dim3(NT, 28), dim3(256), 0, stream, S, Att, Ac, d_sum, adiag);
    hipLaunchKernelGGL(cheb_stream, dim3(2 * NT), dim3(256), 0, stream,
                       x, Ac, d_sum, adiag, thT, xTf, out);
}

// Round 7
// 212.410 us; speedup vs baseline: 1.6925x; 1.0994x over previous
//
#include <hip/hip_runtime.h>

namespace {

typedef __attribute__((ext_vector_type(8)))  short          short8;
typedef __attribute__((ext_vector_type(8)))  unsigned short u16x8;
typedef __attribute__((ext_vector_type(4)))  unsigned short u16x4;
typedef __attribute__((ext_vector_type(4)))  float          f32x4;
typedef __attribute__((ext_vector_type(8)))  _Float16       half8;
typedef __attribute__((ext_vector_type(4)))  _Float16       half4;

constexpr int V  = 200;
constexpr int F  = 64;
constexpr int NT = 512;   // N*T
constexpr int VP = 208;   // 13 x 16

// ---- ws layout (bytes) ----
// Mc  : f16 [512][13 tile][7 kt][64 lane][8]  = 47,710,208  (m = min(S,S^T), frag order)
// xTf : f16 [512][7 kt][4 ft][64 lane][8]     = 14,680,064  (x^T fragments)
// attF: f16 [8][13 tile][7 kt][64 lane][8]    =    745,472  (Att[u][v] fragments, 0 on diag)
// thT : ushort bf16 [3][64][64]               =     24,576
// d   : f32 [512][208] (atomic; holds d-1-S_vv)=   425,984
// adg : f32 [8][208]                          =      6,656
constexpr size_t WS_MC   = 0;
constexpr size_t WS_XTF  = 47710208;
constexpr size_t WS_ATTF = 62390272;
constexpr size_t WS_THT  = 63135744;
constexpr size_t WS_D    = 63160320;
constexpr size_t WS_ADG  = 63586304;   // end 63,592,960

__device__ __forceinline__ unsigned short f2bf(float x) {
    union { float f; unsigned u; } c; c.f = x;
    unsigned r = c.u + 0x7FFF + ((c.u >> 16) & 1);
    return (unsigned short)(r >> 16);
}

// ============ P: merged prep — grid (512, 29) ============
// y < 28 : tile-pair (ti<=tj) S_min -> Mc fragments + d (+adiag, attF on b%64==0)
// y == 28: xTf fragments for batch b; b<3 additionally thT[k=b]
__global__ __launch_bounds__(256)
void prep_all(const float* __restrict__ S,
              const float* __restrict__ Att,
              const float* __restrict__ x,
              const float* __restrict__ Theta,
              _Float16* __restrict__ Mc,
              _Float16* __restrict__ attF,
              _Float16* __restrict__ xTf,
              unsigned short* __restrict__ thT,
              float* __restrict__ d_ws,
              float* __restrict__ adiag)
{
    __shared__ __align__(16) char smem[30464];
    const int b = blockIdx.x, n = b >> 6, tid = threadIdx.x;

    if (blockIdx.y == 28) {
        // ---- xTf path ----
        _Float16* xs = (_Float16*)smem;    // [224][68] f16
        const float* __restrict__ xp = x + (size_t)b * (V * F);
        for (int idx = tid; idx < 224 * 16; idx += 256) {
            const int u = idx >> 4, fg = idx & 15;
            half4 w = (half4)(_Float16)0.f;
            if (u < V) {
                const float4 v4 = *(const float4*)&xp[u * F + 4 * fg];
                w[0] = (_Float16)v4.x; w[1] = (_Float16)v4.y;
                w[2] = (_Float16)v4.z; w[3] = (_Float16)v4.w;
            }
            *(half4*)&xs[u * 68 + 4 * fg] = w;
        }
        __syncthreads();
        // fragment order: frag = kt*4+ft; lane holds x[u=32kt+8q+j][f=16ft+ln]
        _Float16* xo = xTf + (size_t)b * 14336;
        for (int it = 0; it < 7; ++it) {
            const int wid = tid + 256 * it;            // 0..1791
            const int frag = wid >> 6, lane = wid & 63;
            const int kt = frag >> 2, ft = frag & 3;
            const int q = lane >> 4, ln = lane & 15;
            half8 w;
            #pragma unroll
            for (int j = 0; j < 8; ++j)
                w[j] = xs[(32 * kt + 8 * q + j) * 68 + 16 * ft + ln];
            *(half8*)&xo[frag * 512 + lane * 8] = w;
        }
        if (b < 3) {
            // ---- thT[k=b] (bf16, for the epilogue) ----
            const int k = b;
            __syncthreads();                           // xs reads done
            float* T = (float*)smem;                   // [64][65] f32
            for (int idx = tid; idx < 4096; idx += 256)
                T[(idx >> 6) * 65 + (idx & 63)] = Theta[k * 4096 + idx];
            __syncthreads();
            for (int idx = tid; idx < 4096; idx += 256) {
                const int fo = idx >> 6, f = idx & 63;
                thT[k * 4096 + fo * 64 + f] = f2bf(T[f * 65 + fo]);
            }
        }
        return;
    }

    // ---- tile-pair path (verified R6 lineage) ----
    float (*As)[33] = (float(*)[33])smem;                 // S  [ti-rows][tj-cols]
    float (*Bs)[33] = (float(*)[33])(smem + 4224);        // S  [tj-rows][ti-cols]
    float (*Ts)[33] = (float(*)[33])(smem + 8448);        // Att[ti-rows][tj-cols]
    float (*Us)[33] = (float(*)[33])(smem + 12672);       // Att[tj-rows][ti-cols]
    float (*Ms)[33] = (float(*)[33])(smem + 16896);       // min tile (ends 21,120)

    int rem = blockIdx.y, ti = 0;
    while (rem >= 7 - ti) { rem -= 7 - ti; ++ti; }
    const int tj = ti + rem;
    const bool diag = (ti == tj);

    const float* __restrict__ Sp = S   + (size_t)b * (V * V);
    const float* __restrict__ Ap = Att + (size_t)n * (V * V);

    const int r = tid >> 3, cg = tid & 7, c0 = 4 * cg;

    {
        const int gr = 32 * ti + r, gc = 32 * tj + c0;
        float4 a = make_float4(0.f, 0.f, 0.f, 0.f);
        float4 t = make_float4(0.f, 0.f, 0.f, 0.f);
        if (gr < V && gc < V) {
            a = *(const float4*)&Sp[gr * V + gc];
            t = *(const float4*)&Ap[gr * V + gc];
        }
        As[r][c0+0] = a.x; As[r][c0+1] = a.y; As[r][c0+2] = a.z; As[r][c0+3] = a.w;
        Ts[r][c0+0] = t.x; Ts[r][c0+1] = t.y; Ts[r][c0+2] = t.z; Ts[r][c0+3] = t.w;
        if (!diag) {
            const int hr = 32 * tj + r, hc = 32 * ti + c0;
            float4 bb = make_float4(0.f, 0.f, 0.f, 0.f);
            float4 uu = make_float4(0.f, 0.f, 0.f, 0.f);
            if (hr < V && hc < V) {
                bb = *(const float4*)&Sp[hr * V + hc];
                uu = *(const float4*)&Ap[hr * V + hc];
            }
            Bs[r][c0+0] = bb.x; Bs[r][c0+1] = bb.y; Bs[r][c0+2] = bb.z; Bs[r][c0+3] = bb.w;
            Us[r][c0+0] = uu.x; Us[r][c0+1] = uu.y; Us[r][c0+2] = uu.z; Us[r][c0+3] = uu.w;
        }
    }
    __syncthreads();

    // Ms + row-sums -> d[32ti+r]; diag folds -1-S_vv; adiag
    {
        float rs = 0.f;
        #pragma unroll
        for (int e = 0; e < 4; ++e) {
            const int c = c0 + e;
            const float tw = diag ? As[c][r] : Bs[c][r];
            const float m = fminf(As[r][c], tw);
            Ms[r][c] = m;
            rs += m;
        }
        rs += __shfl_xor(rs, 1); rs += __shfl_xor(rs, 2); rs += __shfl_xor(rs, 4);
        const int vg = 32 * ti + r;
        if (cg == 0 && vg < V) {
            const float extra = diag ? (-1.0f - As[r][r]) : 0.0f;
            atomicAdd(&d_ws[b * VP + vg], rs + extra);
            if (diag) adiag[n * VP + vg] = Ts[r][r];
        }
    }
    __syncthreads();   // Ms complete

    if (!diag) {       // col-sums -> d[32tj+r]
        float ts = 0.f;
        #pragma unroll
        for (int e = 0; e < 4; ++e) ts += Ms[c0 + e][r];
        ts += __shfl_xor(ts, 1); ts += __shfl_xor(ts, 2); ts += __shfl_xor(ts, 4);
        if (cg == 0 && 32 * tj + r < V)
            atomicAdd(&d_ws[b * VP + 32 * tj + r], ts);
    }

    // ---- fragment writes (m f16; att f16 once per n) ----
    const int jh = tid & 1, lane = (tid >> 1) & 63, sub = tid >> 7;
    const int rr = lane & 15, qq = lane >> 4;
    const int vl = sub * 16 + rr;          // 0..31 within the 32-row block
    const int ub = 8 * qq + 4 * jh;        // u_local base
    const bool wAtt = ((b & 63) == 0);

    // orientation 1: v in ti-block (tiles 2ti+sub), kt = tj
    if (2 * ti + sub < 13) {
        half4 wm, wa;
        #pragma unroll
        for (int e = 0; e < 4; ++e) {
            const int ul = ub + e;
            wm[e] = (_Float16)Ms[vl][ul];
            const float att = diag ? Ts[ul][vl] : Us[ul][vl];   // Att[u][v]
            wa[e] = (diag && ul == vl) ? (_Float16)0.f : (_Float16)att;
        }
        const size_t base = ((size_t)(b * 13 + 2 * ti + sub) * 7 + tj) * 512 + lane * 8 + jh * 4;
        *(half4*)&Mc[base] = wm;
        if (wAtt) {
            const size_t ab = ((size_t)(n * 13 + 2 * ti + sub) * 7 + tj) * 512 + lane * 8 + jh * 4;
            *(half4*)&attF[ab] = wa;
        }
    }
    // mirror: v in tj-block (tiles 2tj+sub), kt = ti
    if (!diag && 2 * tj + sub < 13) {
        half4 wm, wa;
        #pragma unroll
        for (int e = 0; e < 4; ++e) {
            const int ul = ub + e;
            wm[e] = (_Float16)Ms[ul][vl];          // min(S[v'][u'],S[u'][v'])
            wa[e] = (_Float16)Ts[ul][vl];          // Att[u'=32ti+ul][v'=32tj+vl], u'!=v'
        }
        const size_t base = ((size_t)(b * 13 + 2 * tj + sub) * 7 + ti) * 512 + lane * 8 + jh * 4;
        *(half4*)&Mc[base] = wm;
        if (wAtt) {
            const size_t ab = ((size_t)(n * 13 + 2 * tj + sub) * 7 + ti) * 512 + lane * 8 + jh * 4;
            *(half4*)&attF[ab] = wa;
        }
    }
}

// ============ G: streaming MFMA kernel — in-reg f16 A-build ============
// grid 1024 (XCD-swizzled pairs). Per block: 7 (h=0) / 6 (h=1) v-tiles.
// xTf staged to LDS once; m fragments stream from HBM (double-buffered regs,
// 1KB coalesced wave loads); att fragments from L2 (745KB file). a1 = -m*att,
// a2 = 2m^2*att built in packed f16 regs -> MFMA f16. Epilogue: bf16 (R0 lineage).
__global__ __launch_bounds__(256, 4)
void cheb_stream(const float* __restrict__ x,
                 const _Float16* __restrict__ Mc,
                 const _Float16* __restrict__ attF,
                 const float* __restrict__ d_ws,
                 const float* __restrict__ adiag,
                 const unsigned short* __restrict__ thT,
                 const _Float16* __restrict__ xTf,
                 float* __restrict__ out)
{
    __shared__ __align__(16) char smem[29696];
    _Float16*       xTs = (_Float16*)smem;                  // 28,672 B (K loop)
    unsigned short* ys  = (unsigned short*)smem;            // [112][72] = 16,128 (epi)
    unsigned short* ThS = (unsigned short*)(smem + 16128);  // [64][72]  =  9,216 (epi)
    float* dbuf = (float*)(smem + 28672);                   // [112] c = d-1-S_vv
    float* adb  = (float*)(smem + 29120);                   // [112] Att[v][v]

    const int tid = threadIdx.x;
    const int ub_ = blockIdx.x;
    const int h   = (ub_ >> 3) & 1;
    const int b   = (ub_ & 7) | ((ub_ >> 4) << 3);
    const int n   = b >> 6;
    const int v0  = h * 112;

    // stage xTf -> LDS (coalesced, once)
    const _Float16* __restrict__ xfp = xTf + (size_t)b * 14336;
    #pragma unroll
    for (int it = 0; it < 7; ++it) {
        const int o = it * 2048 + tid * 8;
        *(half8*)&xTs[o] = *(const half8*)&xfp[o];
    }
    if (tid < 112) {
        const int gv = v0 + tid;
        dbuf[tid] = (gv < VP) ? d_ws[b * VP + gv] : 0.f;
        adb[tid]  = (gv < VP) ? adiag[n * VP + gv] : 0.f;
    }

    const int wave = tid >> 6, lane = tid & 63, q = lane >> 4, ln = lane & 15;
    int myBase, myCnt;
    if (h == 0) { myCnt = (wave < 3) ? 2 : 1; myBase = 2 * wave; }
    else        { myCnt = (wave < 2) ? 2 : 1; myBase = (wave < 2) ? 2 * wave : 2 + wave; }

    const float* __restrict__ xp = x + (size_t)b * (V * F);
    float* __restrict__ op = out + (size_t)b * (V * F);

    f32x4 acc1[2][4], acc2[2][4];
    #pragma unroll
    for (int i = 0; i < 2; ++i)
        #pragma unroll
        for (int j = 0; j < 4; ++j) { acc1[i][j] = (f32x4)0.f; acc2[i][j] = (f32x4)0.f; }

    // fragment bases (f16 element index at kt=0); tiles are 7*512 apart
    const size_t fb0 = ((size_t)(b * 13 + 7 * h + myBase) * 7) * 512 + lane * 8;
    const size_t fb1 = fb0 + 7 * 512;
    const size_t af0 = ((size_t)(n * 13 + 7 * h + myBase) * 7) * 512 + lane * 8;
    const size_t af1 = af0 + 7 * 512;

    half8 mc[2] = {}, ac[2] = {}, mn[2] = {}, an[2] = {};
    mc[0] = *(const half8*)&Mc[fb0];
    ac[0] = *(const half8*)&attF[af0];
    if (myCnt > 1) {
        mc[1] = *(const half8*)&Mc[fb1];
        ac[1] = *(const half8*)&attF[af1];
    }
    __syncthreads();   // xTs ready

    #pragma unroll 1
    for (int kt = 0; kt < 7; ++kt) {
        if (kt < 6) {
            const size_t o = (size_t)(kt + 1) * 512;
            mn[0] = *(const half8*)&Mc[fb0 + o];
            an[0] = *(const half8*)&attF[af0 + o];
            if (myCnt > 1) {
                mn[1] = *(const half8*)&Mc[fb1 + o];
                an[1] = *(const half8*)&attF[af1 + o];
            }
        }
        half8 bfr[4];
        #pragma unroll
        for (int ft = 0; ft < 4; ++ft)
            bfr[ft] = *(const half8*)&xTs[(kt * 4 + ft) * 512 + lane * 8];
        #pragma unroll
        for (int vi = 0; vi < 2; ++vi) {
            if (vi < myCnt) {
                const half8 t  = mc[vi] * ac[vi];        // m*att
                const half8 a1 = -t;                     // -m*att
                const half8 a2 = (mc[vi] + mc[vi]) * t;  // 2m^2*att
                #pragma unroll
                for (int ft = 0; ft < 4; ++ft) {
                    acc1[vi][ft] = __builtin_amdgcn_mfma_f32_16x16x32_f16(a1, bfr[ft], acc1[vi][ft], 0, 0, 0);
                    acc2[vi][ft] = __builtin_amdgcn_mfma_f32_16x16x32_f16(a2, bfr[ft], acc2[vi][ft], 0, 0, 0);
                }
            }
        }
        #pragma unroll
        for (int vi = 0; vi < 2; ++vi) { mc[vi] = mn[vi]; ac[vi] = an[vi]; }
    }

    // ---- epilogue: out-tiles += mfma(ys_k, ThT_k) for k = 1, 2, 0 (bf16) ----
    f32x4 ot[2][4];
    #pragma unroll
    for (int i = 0; i < 2; ++i)
        #pragma unroll
        for (int j = 0; j < 4; ++j) ot[i][j] = (f32x4)0.f;

    #pragma unroll
    for (int pass = 0; pass < 3; ++pass) {
        const int k = (pass == 0) ? 1 : (pass == 1) ? 2 : 0;
        __syncthreads();   // K-loop xTs reads done / prev pass MFMA reads done

        if (k == 0) {
            for (int idx = tid; idx < 112 * 16; idx += 256) {
                const int vl = idx >> 4, fg = idx & 15;
                const int v = v0 + vl;
                u16x4 w; w[0] = 0; w[1] = 0; w[2] = 0; w[3] = 0;
                if (v < V) {
                    const float av = adb[vl];
                    const float4 xv = *(const float4*)&xp[v * F + 4 * fg];
                    w[0] = f2bf(av * xv.x); w[1] = f2bf(av * xv.y);
                    w[2] = f2bf(av * xv.z); w[3] = f2bf(av * xv.w);
                }
                *(u16x4*)&ys[vl * 72 + 4 * fg] = w;
            }
        } else {
            #pragma unroll
            for (int vi = 0; vi < 2; ++vi) {
                if (vi < myCnt) {
                    const int lt = myBase + vi;
                    #pragma unroll
                    for (int ft = 0; ft < 4; ++ft) {
                        const f32x4 a = (k == 1) ? acc1[vi][ft] : acc2[vi][ft];
                        #pragma unroll
                        for (int reg = 0; reg < 4; ++reg) {
                            const int vl = lt * 16 + 4 * q + reg;
                            const int v = v0 + vl;
                            float val = 0.f;
                            if (v < V) {
                                const float cc = dbuf[vl];
                                const float dc = ((k == 1) ? cc : (2.0f * cc * cc - 1.0f)) * adb[vl];
                                val = a[reg] + dc * xp[v * F + 16 * ft + ln];
                            }
                            ys[vl * 72 + 16 * ft + ln] = f2bf(val);
                        }
                    }
                }
            }
        }
        for (int idx = tid; idx < 512; idx += 256) {
            const int fo = idx >> 3, ch = idx & 7;
            *(u16x8*)&ThS[fo * 72 + 8 * ch] =
                *(const u16x8*)&thT[k * 4096 + fo * 64 + 8 * ch];
        }
        __syncthreads();
        #pragma unroll
        for (int vi = 0; vi < 2; ++vi) {
            if (vi < myCnt) {
                const int vrow = (myBase + vi) * 16 + ln;
                #pragma unroll
                for (int ks = 0; ks < 2; ++ks) {
                    const short8 af = *(const short8*)&ys[vrow * 72 + 32 * ks + 8 * q];
                    #pragma unroll
                    for (int fot = 0; fot < 4; ++fot) {
                        const short8 bf = *(const short8*)&ThS[(16 * fot + ln) * 72 + 32 * ks + 8 * q];
                        ot[vi][fot] = __builtin_amdgcn_mfma_f32_16x16x32_bf16(af, bf, ot[vi][fot], 0, 0, 0);
                    }
                }
            }
        }
    }

    // ---- relu + store ----
    #pragma unroll
    for (int vi = 0; vi < 2; ++vi) {
        if (vi < myCnt) {
            const int lt = myBase + vi;
            #pragma unroll
            for (int fot = 0; fot < 4; ++fot) {
                #pragma unroll
                for (int reg = 0; reg < 4; ++reg) {
                    const int v = v0 + lt * 16 + 4 * q + reg;
                    if (v < V)
                        op[v * F + 16 * fot + ln] = fmaxf(ot[vi][fot][reg], 0.f);
                }
            }
        }
    }
}

} // namespace

extern "C" void kernel_launch(void* const* d_in, const int* in_sizes, int n_in,
                              void* d_out, int out_size, void* d_ws, size_t ws_size,
                              hipStream_t stream) {
    const float* x     = (const float*)d_in[0];
    const float* Att   = (const float*)d_in[1];
    const float* S     = (const float*)d_in[2];
    const float* Theta = (const float*)d_in[3];
    float* out         = (float*)d_out;

    char* ws = (char*)d_ws;
    _Float16* Mc        = (_Float16*)(ws + WS_MC);
    _Float16* xTf       = (_Float16*)(ws + WS_XTF);
    _Float16* attF      = (_Float16*)(ws + WS_ATTF);
    unsigned short* thT = (unsigned short*)(ws + WS_THT);
    float* d_sum        = (float*)(ws + WS_D);
    float* adiag        = (float*)(ws + WS_ADG);

    // d accumulates via atomicAdd -> must start at 0 every call
    hipMemsetAsync(d_sum, 0, (size_t)NT * VP * sizeof(float), stream);

    hipLaunchKernelGGL(prep_all, dim3(NT, 29), dim3(256), 0, stream,
                       S, Att, x, Theta, Mc, attF, xTf, thT, d_sum, adiag);
    hipLaunchKernelGGL(cheb_stream, dim3(2 * NT), dim3(256), 0, stream,
                       x, Mc, attF, d_sum, adiag, thT, xTf, out);
}